// Round 9
// baseline (855.533 us; speedup 1.0000x reference)
//
#include <hip/hip_runtime.h>
#include <hip/hip_bf16.h>

// Bidirectional ConvLSTM, B=8 T=16 C=3 H=W=32 hid=64 K=7 ('SAME').
// Round 11: RE-TILE block M x N from 256x64 -> 64x256.
//   Root cause finally quantified: old tiling needs 1.68MB of A per CU per
//   step = 51.5 B/cyc = 93% of per-CU L2 BW -> queue-latency inflation =
//   the ~25us/step of bubbles no schedule change could fix (R0-R8 nulls).
//   New block = (dir, b, ygrp8rows, mq=hid-16 quarter): M=64 (4 gates x
//   16 hid -> in-wave epilogue kept), N=256 px. All 4 waves read the SAME
//   4KB A-tile per ks (identical addresses -> L1 broadcast): unique A per
//   CU per step = 420KB (13 B/cyc). B via LDS at 52 B/cyc (<85 ceiling).
//   Inner loop / acc[4][4] / epilogue structure = verified R0/R5 form.
// LDS: h[14][40][72] + XB[8][40][40] = 53,120 shorts = 106,240 B dynamic
//   (attribute path proven in R8; fallback = R5-verified kernel, 644.6us).
//
// Workspace (BYTE offsets), total 13,862,916 B:
//   hp0 : padded h ping, bf16 [dir][b][row38][col40][ic64] @ 0        (3,112,960)
//   hp1 : padded h pong                                    @ 3112960  (3,112,960)
//   c   : cell,  fp32 [dir][b][y32][x32][hid64]            @ 6225920  (4,194,304)
//   wall: bf16 [dir][ks105][oc256][k32]                    @ 10420224 (3,440,640)
//   bias: fp32 [dir][256]                                  @ 13860864 (2,048)
//   flag: int (1 = fp32 inputs)                            @ 13862912 (4)

#define HP0_B  0
#define HP1_B  3112960
#define C_B    6225920
#define WALL_B 10420224
#define BIAS_B 13860864
#define FLAG_B 13862912

#define XBOFF  40320       // shorts: start of XB in LDS
#define LDS_BYTES 106240

using short8 = __attribute__((ext_vector_type(8))) short;
using f32x4  = __attribute__((ext_vector_type(4))) float;

__device__ __forceinline__ float sigm(float x) { return 1.0f / (1.0f + __expf(-x)); }
__device__ __forceinline__ float tanh_f(float x) {
    x = fminf(fmaxf(x, -30.0f), 30.0f);
    float e = __expf(2.0f * x);
    return (e - 1.0f) / (e + 1.0f);
}

// ---- dtype probe (verified) ---------------------------------------------
__global__ void detect_dtype(const unsigned int* __restrict__ xw, int* __restrict__ flag) {
    int lane = threadIdx.x;
    int cnt = 0;
    for (int i = 0; i < 4; ++i) {
        unsigned int w = xw[lane * 4 + i];
        unsigned int e = (w >> 7) & 0xFFu;
        cnt += (e >= 0xC0u) ? 1 : 0;
    }
#pragma unroll
    for (int off = 32; off > 0; off >>= 1) cnt += __shfl_down(cnt, off, 64);
    if (lane == 0) *flag = (cnt > 16) ? 1 : 0;
}

// ---- weights -> wall[d][ks][oc][k32] bf16 + bias ------------------------
__global__ void prep_weights(const void* __restrict__ whhf, const void* __restrict__ whhb,
                             const void* __restrict__ wihf, const void* __restrict__ wihb,
                             const void* __restrict__ bf, const void* __restrict__ bb,
                             short* __restrict__ wall, float* __restrict__ bias_r,
                             const int* __restrict__ flag) {
    int n = blockIdx.x * blockDim.x + threadIdx.x;
    const int fp32 = *flag;
    if (n < 1720320) {
        int icl = n & 31;
        int oc = (n >> 5) & 255;
        int ks = (n >> 13) % 105;
        int d = n / 860160;
        const void* hh = d ? whhb : whhf;
        const void* ih = d ? wihb : wihf;
        float v = 0.0f;
        if (ks < 98) {
            int ky = ks / 14, rr = ks % 14, kc = rr / 7, kx = rr % 7;
            int si = ((oc * 64 + kc * 32 + icl) * 7 + ky) * 7 + kx;
            v = fp32 ? ((const float*)hh)[si] : __bfloat162float(((const __hip_bfloat16*)hh)[si]);
        } else {
            int kx = ks - 98, ky = icl >> 2, ic = icl & 3;
            if (ic < 3 && ky < 7) {
                int si = ((oc * 3 + ic) * 7 + ky) * 7 + kx;
                v = fp32 ? ((const float*)ih)[si] : __bfloat162float(((const __hip_bfloat16*)ih)[si]);
            }
        }
        __hip_bfloat16 hv = __float2bfloat16(v);
        wall[n] = *(short*)&hv;
        return;
    }
    n -= 1720320;
    if (n < 512) {
        const void* src = (n >= 256) ? bb : bf;
        int j = n & 255;
        bias_r[n] = fp32 ? ((const float*)src)[j] : __bfloat162float(((const __hip_bfloat16*)src)[j]);
    }
}

// ---- zero hp0+hp1+c (contiguous 2,605,056 dwords at ws start) -----------
__global__ void zero_state(float* __restrict__ ws_f) {
    int n = blockIdx.x * blockDim.x + threadIdx.x;
    if (n < 2605056) ws_f[n] = 0.0f;
}

// ---- NEW: 64x256-tile MFMA step kernel ----------------------------------
// grid 256 blocks 1D: dir = bit0, mq = bits1-2, b = bits3-5, yg = bits6-7.
// 256 thr = 4 waves; wave wv owns output rows y0+2wv, y0+2wv+1 (64 px),
// all 4 gates x hid[mq*16, mq*16+16) -> acc[4][4], in-wave epilogue.
// All 4 waves read the SAME A tile (4KB/ks) -> L1-broadcast, L2 sees 4KB/ks.
__global__ __launch_bounds__(256, 1)
void lstm_step_mq(const void* __restrict__ xin,
                  const short* __restrict__ wall,
                  const float* __restrict__ bias_r,
                  const unsigned short* __restrict__ hp_r,
                  unsigned short* __restrict__ hp_w,
                  float* __restrict__ c,
                  void* __restrict__ out,
                  const int* __restrict__ flag, int s) {
    extern __shared__ short lds[];
    const int bid = blockIdx.x;
    const int dir = bid & 1;          // XCD=bid%8 -> one dir (and fixed mq) per XCD
    const int mq = (bid >> 1) & 3;    // hid-16 quarter
    const int b = (bid >> 3) & 7;
    const int yg = bid >> 6;          // 0..3
    const int t = dir ? (15 - s) : s;
    const int y0 = yg * 8;
    const int tid = threadIdx.x;
    const int wv = tid >> 6;          // 0..3: rows y0+2wv, y0+2wv+1
    const int ry = 2 * wv;
    const int l = tid & 63;
    const int q = l >> 4;
    const int li = l & 15;
    const int fp32 = *flag;
    const int db = dir * 8 + b;

    // stage h rows y0..y0+13 (padded hp; y0<=24 -> rows <=37 < 38) into LDS
    {
        const uint4* src = (const uint4*)(hp_r + (size_t)(db * 38 + y0) * 40 * 64);
        for (int i = tid; i < 4480; i += 256) {
            int ic8 = i & 7, col = (i >> 3) % 40, row = i / 320;
            uint4 v = src[i];
            *(uint4*)&lds[(row * 40 + col) * 72 + ic8 * 8] = v;
        }
    }
    // build XB[8 rows][40 cols][k=ky*4+ic (40 padded)]
    for (int i = tid; i < 12800; i += 256) {
        int k = i % 40, cc = (i / 40) % 40, r = i / 1600;
        float v = 0.0f;
        if (k < 28) {
            int ky = k >> 2, ic = k & 3;
            int yin = y0 + r + ky - 3, cin = cc - 3;
            if (ic < 3 && yin >= 0 && yin < 32 && cin >= 0 && cin < 32) {
                size_t gi = (size_t)((b * 16 + t) * 3 + ic) * 1024 + yin * 32 + cin;
                v = fp32 ? ((const float*)xin)[gi]
                         : __bfloat162float(((const __hip_bfloat16*)xin)[gi]);
            }
        }
        __hip_bfloat16 hb = __float2bfloat16(v);
        lds[XBOFF + i] = *(short*)&hb;
    }
    __syncthreads();

    // acc init from bias
    f32x4 acc[4][4];
    {
        const float* bp = bias_r + dir * 256 + mq * 16 + q * 4;
#pragma unroll
        for (int g = 0; g < 4; ++g) {
            f32x4 bv = *(const f32x4*)(bp + g * 64);
#pragma unroll
            for (int nt = 0; nt < 4; ++nt) acc[g][nt] = bv;
        }
    }

    // lane bases. A: same addresses for ALL 4 waves (L1 broadcast).
    const short* wbase = wall + (size_t)dir * 860160 + ((mq * 16 + li) * 32 + q * 8);
    int bh[4], bx[4];
#pragma unroll
    for (int nt = 0; nt < 4; ++nt) {
        int rt = nt >> 1, ct = nt & 1;
        bh[nt] = ((ry + rt) * 40 + ct * 16 + li) * 72 + q * 8;
        bx[nt] = XBOFF + ((ry + rt) * 40 + ct * 16 + li) * 40 + q * 8;
    }

    auto loadA = [&](short8* A, int ks) {
        const short* p = wbase + (size_t)ks * 8192;
#pragma unroll
        for (int g = 0; g < 4; ++g) A[g] = *(const short8*)(p + g * 2048);
    };
    auto loadB = [&](short8* B, int ks) {
        if (ks < 98) {
            int ky = ks / 14, rr = ks % 14;
            int uoff = ky * 2880 + (rr % 7) * 72 + (rr / 7) * 32;
#pragma unroll
            for (int nt = 0; nt < 4; ++nt) B[nt] = *(const short8*)&lds[bh[nt] + uoff];
        } else {
            int uoff = (ks - 98) * 40;
#pragma unroll
            for (int nt = 0; nt < 4; ++nt) B[nt] = *(const short8*)&lds[bx[nt] + uoff];
        }
    };
    auto mfma16 = [&](short8* A, short8* B) {
        __builtin_amdgcn_s_setprio(1);
#pragma unroll
        for (int g = 0; g < 4; ++g)
#pragma unroll
            for (int nt = 0; nt < 4; ++nt)
                acc[g][nt] = __builtin_amdgcn_mfma_f32_16x16x32_bf16(A[g], B[nt], acc[g][nt], 0, 0, 0);
        __builtin_amdgcn_s_setprio(0);
    };

    // K-loop: verified 2-deep software pipeline (R0 form), no inline asm.
    short8 A0[4], A1[4], B0[4], B1[4];
    loadA(A0, 0); loadB(B0, 0);
#pragma unroll 1
    for (int ks = 0; ks < 104; ks += 2) {
        loadA(A1, ks + 1); loadB(B1, ks + 1);
        mfma16(A0, B0);
        int kn = (ks + 2 < 105) ? ks + 2 : ks;   // clamp (redundant reload on last)
        loadA(A0, kn); loadB(B0, kn);
        mfma16(A1, B1);
    }
    mfma16(A0, B0);   // ks = 104

    // epilogue (in-wave: all 4 gates present) -- verified form
    const int hid0 = mq * 16 + q * 4;
#pragma unroll
    for (int nt = 0; nt < 4; ++nt) {
        int y = y0 + ry + (nt >> 1);
        int px = (nt & 1) * 16 + li;
        float* cp = c + (size_t)(db * 1024 + y * 32 + px) * 64 + hid0;
        f32x4 cold = *(const f32x4*)cp;
        f32x4 hv;
#pragma unroll
        for (int r = 0; r < 4; ++r) {
            float iv = sigm(acc[0][nt][r]);
            float fv = sigm(acc[1][nt][r]);
            float gv = tanh_f(acc[2][nt][r]);
            float ov = sigm(acc[3][nt][r]);
            float cn = fv * cold[r] + iv * gv;
            cold[r] = cn;
            hv[r] = ov * tanh_f(cn);
        }
        *(f32x4*)cp = cold;

        ushort4 hu;
        {
            __hip_bfloat16 t0 = __float2bfloat16(hv[0]); hu.x = *(unsigned short*)&t0;
            __hip_bfloat16 t1 = __float2bfloat16(hv[1]); hu.y = *(unsigned short*)&t1;
            __hip_bfloat16 t2 = __float2bfloat16(hv[2]); hu.z = *(unsigned short*)&t2;
            __hip_bfloat16 t3 = __float2bfloat16(hv[3]); hu.w = *(unsigned short*)&t3;
        }
        *(ushort4*)(hp_w + (size_t)((db * 38 + y + 3) * 40 + px + 3) * 64 + hid0) = hu;

        size_t ob = (size_t)((b * 16 + t) * 128 + dir * 64 + hid0) * 1024 + y * 32 + px;
        if (fp32) {
            float* op = (float*)out;
#pragma unroll
            for (int r = 0; r < 4; ++r) op[ob + (size_t)r * 1024] = hv[r];
        } else {
            __hip_bfloat16* op = (__hip_bfloat16*)out;
#pragma unroll
            for (int r = 0; r < 4; ++r) op[ob + (size_t)r * 1024] = __float2bfloat16(hv[r]);
        }
    }
}

// ---- FALLBACK: verified R5 kernel (644.6 us, passed) --------------------
__global__ __launch_bounds__(512, 2)
void lstm_step_fb(const void* __restrict__ xin,
                  const short* __restrict__ wall,
                  const float* __restrict__ bias_r,
                  const unsigned short* __restrict__ hp_r,
                  unsigned short* __restrict__ hp_w,
                  float* __restrict__ c,
                  void* __restrict__ out,
                  const int* __restrict__ flag, int s) {
    const int bid = blockIdx.x;
    const int dir = bid & 1;
    const int b = (bid >> 1) & 7;
    const int ygrp = bid >> 4;
    const int t = dir ? (15 - s) : s;
    const int y0 = ygrp * 2;
    const int tid = threadIdx.x;
    const int wv = tid >> 6;
    const int kg = wv >> 2;
    const int wm = wv & 3;
    const int l = tid & 63;
    const int q = l >> 4;
    const int li = l & 15;
    const int fp32 = *flag;
    const int db = dir * 8 + b;

    __shared__ __align__(16) short lds[26240];

    {
        const uint4* src = (const uint4*)(hp_r + (size_t)(db * 38 + y0) * 40 * 64);
        for (int i = tid; i < 2560; i += 512) {
            int ic8 = i & 7, col = (i >> 3) % 40, row = i / 320;
            uint4 v = src[i];
            *(uint4*)&lds[(row * 40 + col) * 72 + ic8 * 8] = v;
        }
    }
    for (int i = tid; i < 3200; i += 512) {
        int k = i % 40, cc = (i / 40) % 40, r = i / 1600;
        float v = 0.0f;
        if (k < 28) {
            int ky = k >> 2, ic = k & 3;
            int yin = y0 + r + ky - 3, cin = cc - 3;
            if (ic < 3 && yin >= 0 && yin < 32 && cin >= 0 && cin < 32) {
                size_t gi = (size_t)((b * 16 + t) * 3 + ic) * 1024 + yin * 32 + cin;
                v = fp32 ? ((const float*)xin)[gi]
                         : __bfloat162float(((const __hip_bfloat16*)xin)[gi]);
            }
        }
        __hip_bfloat16 hb = __float2bfloat16(v);
        lds[23040 + i] = *(short*)&hb;
    }
    __syncthreads();

    f32x4 acc[4][4];
    if (kg == 0) {
        const float* bp = bias_r + dir * 256 + wm * 16 + q * 4;
#pragma unroll
        for (int g = 0; g < 4; ++g) {
            f32x4 bv = *(const f32x4*)(bp + g * 64);
#pragma unroll
            for (int nt = 0; nt < 4; ++nt) acc[g][nt] = bv;
        }
    } else {
        f32x4 z = {0.0f, 0.0f, 0.0f, 0.0f};
#pragma unroll
        for (int g = 0; g < 4; ++g)
#pragma unroll
            for (int nt = 0; nt < 4; ++nt) acc[g][nt] = z;
    }

    const short* wbase = wall + (size_t)dir * 860160 + ((wm * 16 + li) * 32 + q * 8);
    int bh[4], bx[4];
#pragma unroll
    for (int nt = 0; nt < 4; ++nt) {
        int rt = nt >> 1, ct = nt & 1;
        bh[nt] = (rt * 40 + ct * 16 + li) * 72 + q * 8;
        bx[nt] = 23040 + (rt * 40 + ct * 16 + li) * 40 + q * 8;
    }

    auto loadA = [&](short8* A, int ks) {
        const short* p = wbase + (size_t)ks * 8192;
#pragma unroll
        for (int g = 0; g < 4; ++g) A[g] = *(const short8*)(p + g * 2048);
    };
    auto loadB = [&](short8* B, int ks) {
        if (ks < 98) {
            int ky = ks / 14, rr = ks % 14;
            int uoff = ky * 2880 + (rr % 7) * 72 + (rr / 7) * 32;
#pragma unroll
            for (int nt = 0; nt < 4; ++nt) B[nt] = *(const short8*)&lds[bh[nt] + uoff];
        } else {
            int uoff = (ks - 98) * 40;
#pragma unroll
            for (int nt = 0; nt < 4; ++nt) B[nt] = *(const short8*)&lds[bx[nt] + uoff];
        }
    };
    auto mfma16 = [&](short8* A, short8* B) {
        __builtin_amdgcn_s_setprio(1);
#pragma unroll
        for (int g = 0; g < 4; ++g)
#pragma unroll
            for (int nt = 0; nt < 4; ++nt)
                acc[g][nt] = __builtin_amdgcn_mfma_f32_16x16x32_bf16(A[g], B[nt], acc[g][nt], 0, 0, 0);
        __builtin_amdgcn_s_setprio(0);
    };

    const int ks_begin = kg ? 52 : 0;
    const int ks_end   = kg ? 105 : 52;
    short8 A0[4], A1[4], B0[4], B1[4];
    loadA(A0, ks_begin); loadB(B0, ks_begin);
    int ks = ks_begin;
#pragma unroll 1
    for (; ks + 1 < ks_end; ks += 2) {
        loadA(A1, ks + 1); loadB(B1, ks + 1);
        mfma16(A0, B0);
        int kn = (ks + 2 < ks_end) ? ks + 2 : ks;
        loadA(A0, kn); loadB(B0, kn);
        mfma16(A1, B1);
    }
    if (ks < ks_end) mfma16(A0, B0);

    __syncthreads();
    {
        float* exch = (float*)lds;
        float* xp = exch + wm * 2048 + q * 64 + li * 4;
        if (kg == 1) {
#pragma unroll
            for (int g = 0; g < 2; ++g)
#pragma unroll
                for (int nt = 0; nt < 4; ++nt)
                    *(f32x4*)(xp + (g * 4 + nt) * 256) = acc[g][nt];
        }
        __syncthreads();
        if (kg == 0) {
#pragma unroll
            for (int g = 0; g < 2; ++g)
#pragma unroll
                for (int nt = 0; nt < 4; ++nt)
                    acc[g][nt] += *(const f32x4*)(xp + (g * 4 + nt) * 256);
        }
        __syncthreads();
        if (kg == 1) {
#pragma unroll
            for (int g = 0; g < 2; ++g)
#pragma unroll
                for (int nt = 0; nt < 4; ++nt)
                    *(f32x4*)(xp + (g * 4 + nt) * 256) = acc[2 + g][nt];
        }
        __syncthreads();
        if (kg == 0) {
#pragma unroll
            for (int g = 0; g < 2; ++g)
#pragma unroll
                for (int nt = 0; nt < 4; ++nt)
                    acc[2 + g][nt] += *(const f32x4*)(xp + (g * 4 + nt) * 256);
        }
    }
    if (kg == 1) return;

    const int hid0 = wm * 16 + q * 4;
#pragma unroll
    for (int nt = 0; nt < 4; ++nt) {
        int y = y0 + (nt >> 1);
        int px = (nt & 1) * 16 + li;
        float* cp = c + (size_t)(db * 1024 + y * 32 + px) * 64 + hid0;
        f32x4 cold = *(const f32x4*)cp;
        f32x4 hv;
#pragma unroll
        for (int r = 0; r < 4; ++r) {
            float iv = sigm(acc[0][nt][r]);
            float fv = sigm(acc[1][nt][r]);
            float gv = tanh_f(acc[2][nt][r]);
            float ov = sigm(acc[3][nt][r]);
            float cn = fv * cold[r] + iv * gv;
            cold[r] = cn;
            hv[r] = ov * tanh_f(cn);
        }
        *(f32x4*)cp = cold;

        ushort4 hu;
        {
            __hip_bfloat16 t0 = __float2bfloat16(hv[0]); hu.x = *(unsigned short*)&t0;
            __hip_bfloat16 t1 = __float2bfloat16(hv[1]); hu.y = *(unsigned short*)&t1;
            __hip_bfloat16 t2 = __float2bfloat16(hv[2]); hu.z = *(unsigned short*)&t2;
            __hip_bfloat16 t3 = __float2bfloat16(hv[3]); hu.w = *(unsigned short*)&t3;
        }
        *(ushort4*)(hp_w + (size_t)((db * 38 + y + 3) * 40 + px + 3) * 64 + hid0) = hu;

        size_t ob = (size_t)((b * 16 + t) * 128 + dir * 64 + hid0) * 1024 + y * 32 + px;
        if (fp32) {
            float* op = (float*)out;
#pragma unroll
            for (int r = 0; r < 4; ++r) op[ob + (size_t)r * 1024] = hv[r];
        } else {
            __hip_bfloat16* op = (__hip_bfloat16*)out;
#pragma unroll
            for (int r = 0; r < 4; ++r) op[ob + (size_t)r * 1024] = __float2bfloat16(hv[r]);
        }
    }
}

extern "C" void kernel_launch(void* const* d_in, const int* in_sizes, int n_in,
                              void* d_out, int out_size, void* d_ws, size_t ws_size,
                              hipStream_t stream) {
    char* wsb = (char*)d_ws;
    unsigned short* hp0 = (unsigned short*)(wsb + HP0_B);
    unsigned short* hp1 = (unsigned short*)(wsb + HP1_B);
    float* c = (float*)(wsb + C_B);
    short* wall = (short*)(wsb + WALL_B);
    float* bias_r = (float*)(wsb + BIAS_B);
    int* flag = (int*)(wsb + FLAG_B);

    static int big_lds_ok = -1;
    if (big_lds_ok < 0) {
        hipError_t e = hipFuncSetAttribute((const void*)lstm_step_mq,
                                           hipFuncAttributeMaxDynamicSharedMemorySize,
                                           LDS_BYTES);
        big_lds_ok = (e == hipSuccess) ? 1 : 0;
    }

    // inputs: 0=x 1=w_ih_f 2=w_hh_f 3=b_f 4=w_ih_b 5=w_hh_b 6=b_b
    detect_dtype<<<1, 64, 0, stream>>>((const unsigned int*)d_in[0], flag);
    prep_weights<<<6722, 256, 0, stream>>>(d_in[2], d_in[5], d_in[1], d_in[4],
                                           d_in[3], d_in[6], wall, bias_r, flag);
    zero_state<<<10176, 256, 0, stream>>>((float*)d_ws);

    if (big_lds_ok) {
        for (int s = 0; s < 16; ++s) {
            unsigned short* hr = (s & 1) ? hp1 : hp0;
            unsigned short* hw = (s & 1) ? hp0 : hp1;
            lstm_step_mq<<<dim3(256), 256, LDS_BYTES, stream>>>(d_in[0], wall, bias_r,
                                                                hr, hw, c, d_out, flag, s);
        }
    } else {
        for (int s = 0; s < 16; ++s) {
            unsigned short* hr = (s & 1) ? hp1 : hp0;
            unsigned short* hw = (s & 1) ? hp0 : hp1;
            lstm_step_fb<<<dim3(256), 512, 0, stream>>>(d_in[0], wall, bias_r,
                                                        hr, hw, c, d_out, flag, s);
        }
    }
}

// Round 10
// 617.859 us; speedup vs baseline: 1.3847x; 1.3847x over previous
//
#include <hip/hip_runtime.h>
#include <hip/hip_bf16.h>

// Bidirectional ConvLSTM, B=8 T=16 C=3 H=W=32 hid=64 K=7 ('SAME').
// Round 12: R5-verified kernel (644.6us) + coalesced XB build.
//   Change: XB build loop index map k-inner -> cc-inner (i = k*80+r*40+cc),
//   so adjacent lanes read adjacent x elements (coalesced) instead of
//   3,200 scalar strided L2 loads per block per step. Same LDS locations
//   (layout [r][cc][k40]; kx handled by +40/kx shift at read, unchanged).
// Everything else byte-identical to the Round-5 bench (passed, 644.6us):
//   8 waves = 4 M-split x 2 K-split, 2-deep pipe, dir-in-LSB grid,
//   setprio around MFMA, LDS exchange in 2 halves, in-wave epilogue.
//
// Workspace (BYTE offsets), total 13,862,916 B:
//   hp0 : padded h ping, bf16 [dir][b][row38][col40][ic64] @ 0        (3,112,960)
//   hp1 : padded h pong                                    @ 3112960  (3,112,960)
//   c   : cell,  fp32 [dir][b][y32][x32][hid64]            @ 6225920  (4,194,304)
//   wall: bf16 [dir][ks105][oc256][k32]                    @ 10420224 (3,440,640)
//   bias: fp32 [dir][256]                                  @ 13860864 (2,048)
//   flag: int (1 = fp32 inputs)                            @ 13862912 (4)

#define HP0_B  0
#define HP1_B  3112960
#define C_B    6225920
#define WALL_B 10420224
#define BIAS_B 13860864
#define FLAG_B 13862912

using short8 = __attribute__((ext_vector_type(8))) short;
using f32x4  = __attribute__((ext_vector_type(4))) float;

__device__ __forceinline__ float sigm(float x) { return 1.0f / (1.0f + __expf(-x)); }
__device__ __forceinline__ float tanh_f(float x) {
    x = fminf(fmaxf(x, -30.0f), 30.0f);
    float e = __expf(2.0f * x);
    return (e - 1.0f) / (e + 1.0f);
}

// ---- dtype probe (verified) ---------------------------------------------
__global__ void detect_dtype(const unsigned int* __restrict__ xw, int* __restrict__ flag) {
    int lane = threadIdx.x;
    int cnt = 0;
    for (int i = 0; i < 4; ++i) {
        unsigned int w = xw[lane * 4 + i];
        unsigned int e = (w >> 7) & 0xFFu;
        cnt += (e >= 0xC0u) ? 1 : 0;
    }
#pragma unroll
    for (int off = 32; off > 0; off >>= 1) cnt += __shfl_down(cnt, off, 64);
    if (lane == 0) *flag = (cnt > 16) ? 1 : 0;
}

// ---- weights -> wall[d][ks][oc][k32] bf16 + bias ------------------------
__global__ void prep_weights(const void* __restrict__ whhf, const void* __restrict__ whhb,
                             const void* __restrict__ wihf, const void* __restrict__ wihb,
                             const void* __restrict__ bf, const void* __restrict__ bb,
                             short* __restrict__ wall, float* __restrict__ bias_r,
                             const int* __restrict__ flag) {
    int n = blockIdx.x * blockDim.x + threadIdx.x;
    const int fp32 = *flag;
    if (n < 1720320) {
        int icl = n & 31;
        int oc = (n >> 5) & 255;
        int ks = (n >> 13) % 105;
        int d = n / 860160;
        const void* hh = d ? whhb : whhf;
        const void* ih = d ? wihb : wihf;
        float v = 0.0f;
        if (ks < 98) {
            int ky = ks / 14, rr = ks % 14, kc = rr / 7, kx = rr % 7;
            int si = ((oc * 64 + kc * 32 + icl) * 7 + ky) * 7 + kx;
            v = fp32 ? ((const float*)hh)[si] : __bfloat162float(((const __hip_bfloat16*)hh)[si]);
        } else {
            int kx = ks - 98, ky = icl >> 2, ic = icl & 3;
            if (ic < 3 && ky < 7) {
                int si = ((oc * 3 + ic) * 7 + ky) * 7 + kx;
                v = fp32 ? ((const float*)ih)[si] : __bfloat162float(((const __hip_bfloat16*)ih)[si]);
            }
        }
        __hip_bfloat16 hv = __float2bfloat16(v);
        wall[n] = *(short*)&hv;
        return;
    }
    n -= 1720320;
    if (n < 512) {
        const void* src = (n >= 256) ? bb : bf;
        int j = n & 255;
        bias_r[n] = fp32 ? ((const float*)src)[j] : __bfloat162float(((const __hip_bfloat16*)src)[j]);
    }
}

// ---- zero hp0+hp1+c (contiguous 2,605,056 dwords at ws start) -----------
__global__ void zero_state(float* __restrict__ ws_f) {
    int n = blockIdx.x * blockDim.x + threadIdx.x;
    if (n < 2605056) ws_f[n] = 0.0f;
}

// ---- MFMA step kernel ----------------------------------------------------
// grid 256 blocks 1D (bid: dir = bit0, b = bits1-3, ygrp = bits4-7), 512 thr
// = 8 waves (4 M-split x 2 K-split).
// LDS (52,480 B static), overlaid:
//   K-loop  : h tile [8][40][72] + XB [2][40][40] = 26240 shorts (52,480 B)
//   exchange: kg=1 partial acc half, fp32 (32,768 B, overlays h-tile region)
__global__ __launch_bounds__(512, 2)
void lstm_step(const void* __restrict__ xin,
               const short* __restrict__ wall,
               const float* __restrict__ bias_r,
               const unsigned short* __restrict__ hp_r,
               unsigned short* __restrict__ hp_w,
               float* __restrict__ c,
               void* __restrict__ out,
               const int* __restrict__ flag, int s) {
    const int bid = blockIdx.x;
    const int dir = bid & 1;          // dir in LSB: XCD=bid%8 -> one dir per XCD
    const int b = (bid >> 1) & 7;
    const int ygrp = bid >> 4;
    const int t = dir ? (15 - s) : s;
    const int y0 = ygrp * 2;
    const int tid = threadIdx.x;
    const int wv = tid >> 6;          // 0..7
    const int kg = wv >> 2;           // K-group: 0 -> ks [0,52), 1 -> ks [52,105)
    const int wm = wv & 3;            // M-split role
    const int l = tid & 63;
    const int q = l >> 4;
    const int li = l & 15;
    const int fp32 = *flag;
    const int db = dir * 8 + b;

    __shared__ __align__(16) short lds[26240];

    // stage h rows y0..y0+7 (contiguous in global) into padded LDS
    {
        const uint4* src = (const uint4*)(hp_r + (size_t)(db * 38 + y0) * 40 * 64);
        for (int i = tid; i < 2560; i += 512) {
            int ic8 = i & 7, col = (i >> 3) % 40, row = i / 320;
            uint4 v = src[i];
            *(uint4*)&lds[(row * 40 + col) * 72 + ic8 * 8] = v;
        }
    }
    // build XB[r][cc][k=ky*4+ic] -- cc-inner index map: adjacent lanes read
    // adjacent x elements (coalesced). Same LDS locations as verified layout.
    for (int i = tid; i < 3200; i += 512) {
        int cc = i % 40;
        int r  = (i / 40) & 1;
        int k  = i / 80;              // 0..39
        float v = 0.0f;
        if (k < 28) {
            int ky = k >> 2, ic = k & 3;
            int yin = y0 + r + ky - 3, cin = cc - 3;
            if (ic < 3 && yin >= 0 && yin < 32 && cin >= 0 && cin < 32) {
                size_t gi = (size_t)((b * 16 + t) * 3 + ic) * 1024 + yin * 32 + cin;
                v = fp32 ? ((const float*)xin)[gi]
                         : __bfloat162float(((const __hip_bfloat16*)xin)[gi]);
            }
        }
        __hip_bfloat16 hb = __float2bfloat16(v);
        lds[23040 + (r * 40 + cc) * 40 + k] = *(short*)&hb;
    }
    __syncthreads();

    // acc init: kg=0 carries the bias, kg=1 starts at zero (partials)
    f32x4 acc[4][4];
    if (kg == 0) {
        const float* bp = bias_r + dir * 256 + wm * 16 + q * 4;
#pragma unroll
        for (int g = 0; g < 4; ++g) {
            f32x4 bv = *(const f32x4*)(bp + g * 64);
#pragma unroll
            for (int nt = 0; nt < 4; ++nt) acc[g][nt] = bv;
        }
    } else {
        f32x4 z = {0.0f, 0.0f, 0.0f, 0.0f};
#pragma unroll
        for (int g = 0; g < 4; ++g)
#pragma unroll
            for (int nt = 0; nt < 4; ++nt) acc[g][nt] = z;
    }

    // lane bases
    const short* wbase = wall + (size_t)dir * 860160 + ((wm * 16 + li) * 32 + q * 8);
    int bh[4], bx[4];
#pragma unroll
    for (int nt = 0; nt < 4; ++nt) {
        int rt = nt >> 1, ct = nt & 1;
        bh[nt] = (rt * 40 + ct * 16 + li) * 72 + q * 8;
        bx[nt] = 23040 + (rt * 40 + ct * 16 + li) * 40 + q * 8;
    }

    auto loadA = [&](short8* A, int ks) {
        const short* p = wbase + (size_t)ks * 8192;
#pragma unroll
        for (int g = 0; g < 4; ++g) A[g] = *(const short8*)(p + g * 2048);
    };
    auto loadB = [&](short8* B, int ks) {
        if (ks < 98) {
            int ky = ks / 14, rr = ks % 14;
            int uoff = ky * 2880 + (rr % 7) * 72 + (rr / 7) * 32;
#pragma unroll
            for (int nt = 0; nt < 4; ++nt) B[nt] = *(const short8*)&lds[bh[nt] + uoff];
        } else {
            int uoff = (ks - 98) * 40;
#pragma unroll
            for (int nt = 0; nt < 4; ++nt) B[nt] = *(const short8*)&lds[bx[nt] + uoff];
        }
    };
    auto mfma16 = [&](short8* A, short8* B) {
        __builtin_amdgcn_s_setprio(1);      // T5
#pragma unroll
        for (int g = 0; g < 4; ++g)
#pragma unroll
            for (int nt = 0; nt < 4; ++nt)
                acc[g][nt] = __builtin_amdgcn_mfma_f32_16x16x32_bf16(A[g], B[nt], acc[g][nt], 0, 0, 0);
        __builtin_amdgcn_s_setprio(0);
    };

    // K-loop over this wave-group's slice, 2-deep software pipeline
    const int ks_begin = kg ? 52 : 0;
    const int ks_end   = kg ? 105 : 52;
    short8 A0[4], A1[4], B0[4], B1[4];
    loadA(A0, ks_begin); loadB(B0, ks_begin);
    int ks = ks_begin;
#pragma unroll 1
    for (; ks + 1 < ks_end; ks += 2) {
        loadA(A1, ks + 1); loadB(B1, ks + 1);
        mfma16(A0, B0);
        int kn = (ks + 2 < ks_end) ? ks + 2 : ks; // clamp (redundant reload on last iter)
        loadA(A0, kn); loadB(B0, kn);
        mfma16(A1, B1);
    }
    if (ks < ks_end) mfma16(A0, B0); // odd-count tail (kg=1: ks=104)

    // ---- combine partials: kg=1 -> LDS -> kg=0 adds (two 32 KiB halves) --
    // Fully unrolled, CONSTANT acc indices only (rule #20: no runtime index).
    __syncthreads();           // all waves done with h-tile/XB reads
    {
        float* exch = (float*)lds;
        float* xp = exch + wm * 2048 + q * 64 + li * 4;
        // half 0: gates 0,1
        if (kg == 1) {
#pragma unroll
            for (int g = 0; g < 2; ++g)
#pragma unroll
                for (int nt = 0; nt < 4; ++nt)
                    *(f32x4*)(xp + (g * 4 + nt) * 256) = acc[g][nt];
        }
        __syncthreads();
        if (kg == 0) {
#pragma unroll
            for (int g = 0; g < 2; ++g)
#pragma unroll
                for (int nt = 0; nt < 4; ++nt)
                    acc[g][nt] += *(const f32x4*)(xp + (g * 4 + nt) * 256);
        }
        __syncthreads();
        // half 1: gates 2,3
        if (kg == 1) {
#pragma unroll
            for (int g = 0; g < 2; ++g)
#pragma unroll
                for (int nt = 0; nt < 4; ++nt)
                    *(f32x4*)(xp + (g * 4 + nt) * 256) = acc[2 + g][nt];
        }
        __syncthreads();
        if (kg == 0) {
#pragma unroll
            for (int g = 0; g < 2; ++g)
#pragma unroll
                for (int nt = 0; nt < 4; ++nt)
                    acc[2 + g][nt] += *(const f32x4*)(xp + (g * 4 + nt) * 256);
        }
    }
    if (kg == 1) return;       // no barriers past this point

    // epilogue (kg=0 only; all 4 gates present in-wave) -- unchanged
    const int hid0 = wm * 16 + q * 4;
#pragma unroll
    for (int nt = 0; nt < 4; ++nt) {
        int y = y0 + (nt >> 1);
        int px = (nt & 1) * 16 + li;
        float* cp = c + (size_t)(db * 1024 + y * 32 + px) * 64 + hid0;
        f32x4 cold = *(const f32x4*)cp;
        f32x4 hv;
#pragma unroll
        for (int r = 0; r < 4; ++r) {
            float iv = sigm(acc[0][nt][r]);
            float fv = sigm(acc[1][nt][r]);
            float gv = tanh_f(acc[2][nt][r]);
            float ov = sigm(acc[3][nt][r]);
            float cn = fv * cold[r] + iv * gv;
            cold[r] = cn;
            hv[r] = ov * tanh_f(cn);
        }
        *(f32x4*)cp = cold;

        ushort4 hu;
        {
            __hip_bfloat16 t0 = __float2bfloat16(hv[0]); hu.x = *(unsigned short*)&t0;
            __hip_bfloat16 t1 = __float2bfloat16(hv[1]); hu.y = *(unsigned short*)&t1;
            __hip_bfloat16 t2 = __float2bfloat16(hv[2]); hu.z = *(unsigned short*)&t2;
            __hip_bfloat16 t3 = __float2bfloat16(hv[3]); hu.w = *(unsigned short*)&t3;
        }
        *(ushort4*)(hp_w + (size_t)((db * 38 + y + 3) * 40 + px + 3) * 64 + hid0) = hu;

        size_t ob = (size_t)((b * 16 + t) * 128 + dir * 64 + hid0) * 1024 + y * 32 + px;
        if (fp32) {
            float* op = (float*)out;
#pragma unroll
            for (int r = 0; r < 4; ++r) op[ob + (size_t)r * 1024] = hv[r];
        } else {
            __hip_bfloat16* op = (__hip_bfloat16*)out;
#pragma unroll
            for (int r = 0; r < 4; ++r) op[ob + (size_t)r * 1024] = __float2bfloat16(hv[r]);
        }
    }
}

extern "C" void kernel_launch(void* const* d_in, const int* in_sizes, int n_in,
                              void* d_out, int out_size, void* d_ws, size_t ws_size,
                              hipStream_t stream) {
    char* wsb = (char*)d_ws;
    unsigned short* hp0 = (unsigned short*)(wsb + HP0_B);
    unsigned short* hp1 = (unsigned short*)(wsb + HP1_B);
    float* c = (float*)(wsb + C_B);
    short* wall = (short*)(wsb + WALL_B);
    float* bias_r = (float*)(wsb + BIAS_B);
    int* flag = (int*)(wsb + FLAG_B);

    // inputs: 0=x 1=w_ih_f 2=w_hh_f 3=b_f 4=w_ih_b 5=w_hh_b 6=b_b
    detect_dtype<<<1, 64, 0, stream>>>((const unsigned int*)d_in[0], flag);
    prep_weights<<<6722, 256, 0, stream>>>(d_in[2], d_in[5], d_in[1], d_in[4],
                                           d_in[3], d_in[6], wall, bias_r, flag);
    zero_state<<<10176, 256, 0, stream>>>((float*)d_ws);

    for (int s = 0; s < 16; ++s) {
        unsigned short* hr = (s & 1) ? hp1 : hp0;
        unsigned short* hw = (s & 1) ? hp0 : hp1;
        lstm_step<<<dim3(256), 512, 0, stream>>>(d_in[0], wall, bias_r,
                                                 hr, hw, c, d_out, flag, s);
    }
}

// Round 11
// 592.426 us; speedup vs baseline: 1.4441x; 1.0429x over previous
//
#include <hip/hip_runtime.h>
#include <hip/hip_bf16.h>

// Bidirectional ConvLSTM, B=8 T=16 C=3 H=W=32 hid=64 K=7 ('SAME').
// Round 13: R10-verified kernel (617.9us) + s==0 fast path.
//   At s=0, h_prev == 0 exactly (workspace zeroed): the 98 h-conv K-steps
//   are dead work (W_hh*0 = 0, bit-exact). For s==0: kg0 runs ks [98,101),
//   kg1 runs ks [101,105), h-tile staging skipped. ~93% of step-0 gone.
// Everything else byte-identical to Round-10 bench (passed, 617.9us):
//   8 waves = 4 M-split x 2 K-split, 2-deep pipe, dir-in-LSB grid,
//   setprio around MFMA, coalesced XB build, LDS exchange, in-wave epilogue.
//
// Workspace (BYTE offsets), total 13,862,916 B:
//   hp0 : padded h ping, bf16 [dir][b][row38][col40][ic64] @ 0        (3,112,960)
//   hp1 : padded h pong                                    @ 3112960  (3,112,960)
//   c   : cell,  fp32 [dir][b][y32][x32][hid64]            @ 6225920  (4,194,304)
//   wall: bf16 [dir][ks105][oc256][k32]                    @ 10420224 (3,440,640)
//   bias: fp32 [dir][256]                                  @ 13860864 (2,048)
//   flag: int (1 = fp32 inputs)                            @ 13862912 (4)

#define HP0_B  0
#define HP1_B  3112960
#define C_B    6225920
#define WALL_B 10420224
#define BIAS_B 13860864
#define FLAG_B 13862912

using short8 = __attribute__((ext_vector_type(8))) short;
using f32x4  = __attribute__((ext_vector_type(4))) float;

__device__ __forceinline__ float sigm(float x) { return 1.0f / (1.0f + __expf(-x)); }
__device__ __forceinline__ float tanh_f(float x) {
    x = fminf(fmaxf(x, -30.0f), 30.0f);
    float e = __expf(2.0f * x);
    return (e - 1.0f) / (e + 1.0f);
}

// ---- dtype probe (verified) ---------------------------------------------
__global__ void detect_dtype(const unsigned int* __restrict__ xw, int* __restrict__ flag) {
    int lane = threadIdx.x;
    int cnt = 0;
    for (int i = 0; i < 4; ++i) {
        unsigned int w = xw[lane * 4 + i];
        unsigned int e = (w >> 7) & 0xFFu;
        cnt += (e >= 0xC0u) ? 1 : 0;
    }
#pragma unroll
    for (int off = 32; off > 0; off >>= 1) cnt += __shfl_down(cnt, off, 64);
    if (lane == 0) *flag = (cnt > 16) ? 1 : 0;
}

// ---- weights -> wall[d][ks][oc][k32] bf16 + bias ------------------------
__global__ void prep_weights(const void* __restrict__ whhf, const void* __restrict__ whhb,
                             const void* __restrict__ wihf, const void* __restrict__ wihb,
                             const void* __restrict__ bf, const void* __restrict__ bb,
                             short* __restrict__ wall, float* __restrict__ bias_r,
                             const int* __restrict__ flag) {
    int n = blockIdx.x * blockDim.x + threadIdx.x;
    const int fp32 = *flag;
    if (n < 1720320) {
        int icl = n & 31;
        int oc = (n >> 5) & 255;
        int ks = (n >> 13) % 105;
        int d = n / 860160;
        const void* hh = d ? whhb : whhf;
        const void* ih = d ? wihb : wihf;
        float v = 0.0f;
        if (ks < 98) {
            int ky = ks / 14, rr = ks % 14, kc = rr / 7, kx = rr % 7;
            int si = ((oc * 64 + kc * 32 + icl) * 7 + ky) * 7 + kx;
            v = fp32 ? ((const float*)hh)[si] : __bfloat162float(((const __hip_bfloat16*)hh)[si]);
        } else {
            int kx = ks - 98, ky = icl >> 2, ic = icl & 3;
            if (ic < 3 && ky < 7) {
                int si = ((oc * 3 + ic) * 7 + ky) * 7 + kx;
                v = fp32 ? ((const float*)ih)[si] : __bfloat162float(((const __hip_bfloat16*)ih)[si]);
            }
        }
        __hip_bfloat16 hv = __float2bfloat16(v);
        wall[n] = *(short*)&hv;
        return;
    }
    n -= 1720320;
    if (n < 512) {
        const void* src = (n >= 256) ? bb : bf;
        int j = n & 255;
        bias_r[n] = fp32 ? ((const float*)src)[j] : __bfloat162float(((const __hip_bfloat16*)src)[j]);
    }
}

// ---- zero hp0+hp1+c (contiguous 2,605,056 dwords at ws start) -----------
__global__ void zero_state(float* __restrict__ ws_f) {
    int n = blockIdx.x * blockDim.x + threadIdx.x;
    if (n < 2605056) ws_f[n] = 0.0f;
}

// ---- MFMA step kernel ----------------------------------------------------
// grid 256 blocks 1D (bid: dir = bit0, b = bits1-3, ygrp = bits4-7), 512 thr
// = 8 waves (4 M-split x 2 K-split).
// LDS (52,480 B static), overlaid:
//   K-loop  : h tile [8][40][72] + XB [2][40][40] = 26240 shorts (52,480 B)
//   exchange: kg=1 partial acc half, fp32 (32,768 B, overlays h-tile region)
__global__ __launch_bounds__(512, 2)
void lstm_step(const void* __restrict__ xin,
               const short* __restrict__ wall,
               const float* __restrict__ bias_r,
               const unsigned short* __restrict__ hp_r,
               unsigned short* __restrict__ hp_w,
               float* __restrict__ c,
               void* __restrict__ out,
               const int* __restrict__ flag, int s) {
    const int bid = blockIdx.x;
    const int dir = bid & 1;          // dir in LSB: XCD=bid%8 -> one dir per XCD
    const int b = (bid >> 1) & 7;
    const int ygrp = bid >> 4;
    const int t = dir ? (15 - s) : s;
    const int y0 = ygrp * 2;
    const int tid = threadIdx.x;
    const int wv = tid >> 6;          // 0..7
    const int kg = wv >> 2;           // K-group
    const int wm = wv & 3;            // M-split role
    const int l = tid & 63;
    const int q = l >> 4;
    const int li = l & 15;
    const int fp32 = *flag;
    const int db = dir * 8 + b;

    __shared__ __align__(16) short lds[26240];

    // stage h rows y0..y0+7 into padded LDS -- SKIPPED at s==0 (h==0; the
    // s==0 K-range below never reads the h region).
    if (s != 0) {
        const uint4* src = (const uint4*)(hp_r + (size_t)(db * 38 + y0) * 40 * 64);
        for (int i = tid; i < 2560; i += 512) {
            int ic8 = i & 7, col = (i >> 3) % 40, row = i / 320;
            uint4 v = src[i];
            *(uint4*)&lds[(row * 40 + col) * 72 + ic8 * 8] = v;
        }
    }
    // build XB[r][cc][k=ky*4+ic] -- cc-inner index map (coalesced, R10 win)
    for (int i = tid; i < 3200; i += 512) {
        int cc = i % 40;
        int r  = (i / 40) & 1;
        int k  = i / 80;              // 0..39
        float v = 0.0f;
        if (k < 28) {
            int ky = k >> 2, ic = k & 3;
            int yin = y0 + r + ky - 3, cin = cc - 3;
            if (ic < 3 && yin >= 0 && yin < 32 && cin >= 0 && cin < 32) {
                size_t gi = (size_t)((b * 16 + t) * 3 + ic) * 1024 + yin * 32 + cin;
                v = fp32 ? ((const float*)xin)[gi]
                         : __bfloat162float(((const __hip_bfloat16*)xin)[gi]);
            }
        }
        __hip_bfloat16 hb = __float2bfloat16(v);
        lds[23040 + (r * 40 + cc) * 40 + k] = *(short*)&hb;
    }
    __syncthreads();

    // acc init: kg=0 carries the bias, kg=1 starts at zero (partials)
    f32x4 acc[4][4];
    if (kg == 0) {
        const float* bp = bias_r + dir * 256 + wm * 16 + q * 4;
#pragma unroll
        for (int g = 0; g < 4; ++g) {
            f32x4 bv = *(const f32x4*)(bp + g * 64);
#pragma unroll
            for (int nt = 0; nt < 4; ++nt) acc[g][nt] = bv;
        }
    } else {
        f32x4 z = {0.0f, 0.0f, 0.0f, 0.0f};
#pragma unroll
        for (int g = 0; g < 4; ++g)
#pragma unroll
            for (int nt = 0; nt < 4; ++nt) acc[g][nt] = z;
    }

    // lane bases
    const short* wbase = wall + (size_t)dir * 860160 + ((wm * 16 + li) * 32 + q * 8);
    int bh[4], bx[4];
#pragma unroll
    for (int nt = 0; nt < 4; ++nt) {
        int rt = nt >> 1, ct = nt & 1;
        bh[nt] = (rt * 40 + ct * 16 + li) * 72 + q * 8;
        bx[nt] = 23040 + (rt * 40 + ct * 16 + li) * 40 + q * 8;
    }

    auto loadA = [&](short8* A, int ks) {
        const short* p = wbase + (size_t)ks * 8192;
#pragma unroll
        for (int g = 0; g < 4; ++g) A[g] = *(const short8*)(p + g * 2048);
    };
    auto loadB = [&](short8* B, int ks) {
        if (ks < 98) {
            int ky = ks / 14, rr = ks % 14;
            int uoff = ky * 2880 + (rr % 7) * 72 + (rr / 7) * 32;
#pragma unroll
            for (int nt = 0; nt < 4; ++nt) B[nt] = *(const short8*)&lds[bh[nt] + uoff];
        } else {
            int uoff = (ks - 98) * 40;
#pragma unroll
            for (int nt = 0; nt < 4; ++nt) B[nt] = *(const short8*)&lds[bx[nt] + uoff];
        }
    };
    auto mfma16 = [&](short8* A, short8* B) {
        __builtin_amdgcn_s_setprio(1);      // T5
#pragma unroll
        for (int g = 0; g < 4; ++g)
#pragma unroll
            for (int nt = 0; nt < 4; ++nt)
                acc[g][nt] = __builtin_amdgcn_mfma_f32_16x16x32_bf16(A[g], B[nt], acc[g][nt], 0, 0, 0);
        __builtin_amdgcn_s_setprio(0);
    };

    // K-loop ranges: s==0 -> h==0 exactly, only x-conv ks [98,105) needed
    // (bit-exact shortcut). Else full [0,105) split at 52.
    const int ks_begin = (s == 0) ? (kg ? 101 : 98) : (kg ? 52 : 0);
    const int ks_end   = (s == 0) ? (kg ? 105 : 101) : (kg ? 105 : 52);
    short8 A0[4], A1[4], B0[4], B1[4];
    loadA(A0, ks_begin); loadB(B0, ks_begin);
    int ks = ks_begin;
#pragma unroll 1
    for (; ks + 1 < ks_end; ks += 2) {
        loadA(A1, ks + 1); loadB(B1, ks + 1);
        mfma16(A0, B0);
        int kn = (ks + 2 < ks_end) ? ks + 2 : ks; // clamp (redundant reload on last iter)
        loadA(A0, kn); loadB(B0, kn);
        mfma16(A1, B1);
    }
    if (ks < ks_end) mfma16(A0, B0); // odd-count tail

    // ---- combine partials: kg=1 -> LDS -> kg=0 adds (two 32 KiB halves) --
    __syncthreads();           // all waves done with h-tile/XB reads
    {
        float* exch = (float*)lds;
        float* xp = exch + wm * 2048 + q * 64 + li * 4;
        // half 0: gates 0,1
        if (kg == 1) {
#pragma unroll
            for (int g = 0; g < 2; ++g)
#pragma unroll
                for (int nt = 0; nt < 4; ++nt)
                    *(f32x4*)(xp + (g * 4 + nt) * 256) = acc[g][nt];
        }
        __syncthreads();
        if (kg == 0) {
#pragma unroll
            for (int g = 0; g < 2; ++g)
#pragma unroll
                for (int nt = 0; nt < 4; ++nt)
                    acc[g][nt] += *(const f32x4*)(xp + (g * 4 + nt) * 256);
        }
        __syncthreads();
        // half 1: gates 2,3
        if (kg == 1) {
#pragma unroll
            for (int g = 0; g < 2; ++g)
#pragma unroll
                for (int nt = 0; nt < 4; ++nt)
                    *(f32x4*)(xp + (g * 4 + nt) * 256) = acc[2 + g][nt];
        }
        __syncthreads();
        if (kg == 0) {
#pragma unroll
            for (int g = 0; g < 2; ++g)
#pragma unroll
                for (int nt = 0; nt < 4; ++nt)
                    acc[2 + g][nt] += *(const f32x4*)(xp + (g * 4 + nt) * 256);
        }
    }
    if (kg == 1) return;       // no barriers past this point

    // epilogue (kg=0 only; all 4 gates present in-wave) -- unchanged
    const int hid0 = wm * 16 + q * 4;
#pragma unroll
    for (int nt = 0; nt < 4; ++nt) {
        int y = y0 + (nt >> 1);
        int px = (nt & 1) * 16 + li;
        float* cp = c + (size_t)(db * 1024 + y * 32 + px) * 64 + hid0;
        f32x4 cold = *(const f32x4*)cp;
        f32x4 hv;
#pragma unroll
        for (int r = 0; r < 4; ++r) {
            float iv = sigm(acc[0][nt][r]);
            float fv = sigm(acc[1][nt][r]);
            float gv = tanh_f(acc[2][nt][r]);
            float ov = sigm(acc[3][nt][r]);
            float cn = fv * cold[r] + iv * gv;
            cold[r] = cn;
            hv[r] = ov * tanh_f(cn);
        }
        *(f32x4*)cp = cold;

        ushort4 hu;
        {
            __hip_bfloat16 t0 = __float2bfloat16(hv[0]); hu.x = *(unsigned short*)&t0;
            __hip_bfloat16 t1 = __float2bfloat16(hv[1]); hu.y = *(unsigned short*)&t1;
            __hip_bfloat16 t2 = __float2bfloat16(hv[2]); hu.z = *(unsigned short*)&t2;
            __hip_bfloat16 t3 = __float2bfloat16(hv[3]); hu.w = *(unsigned short*)&t3;
        }
        *(ushort4*)(hp_w + (size_t)((db * 38 + y + 3) * 40 + px + 3) * 64 + hid0) = hu;

        size_t ob = (size_t)((b * 16 + t) * 128 + dir * 64 + hid0) * 1024 + y * 32 + px;
        if (fp32) {
            float* op = (float*)out;
#pragma unroll
            for (int r = 0; r < 4; ++r) op[ob + (size_t)r * 1024] = hv[r];
        } else {
            __hip_bfloat16* op = (__hip_bfloat16*)out;
#pragma unroll
            for (int r = 0; r < 4; ++r) op[ob + (size_t)r * 1024] = __float2bfloat16(hv[r]);
        }
    }
}

extern "C" void kernel_launch(void* const* d_in, const int* in_sizes, int n_in,
                              void* d_out, int out_size, void* d_ws, size_t ws_size,
                              hipStream_t stream) {
    char* wsb = (char*)d_ws;
    unsigned short* hp0 = (unsigned short*)(wsb + HP0_B);
    unsigned short* hp1 = (unsigned short*)(wsb + HP1_B);
    float* c = (float*)(wsb + C_B);
    short* wall = (short*)(wsb + WALL_B);
    float* bias_r = (float*)(wsb + BIAS_B);
    int* flag = (int*)(wsb + FLAG_B);

    // inputs: 0=x 1=w_ih_f 2=w_hh_f 3=b_f 4=w_ih_b 5=w_hh_b 6=b_b
    detect_dtype<<<1, 64, 0, stream>>>((const unsigned int*)d_in[0], flag);
    prep_weights<<<6722, 256, 0, stream>>>(d_in[2], d_in[5], d_in[1], d_in[4],
                                           d_in[3], d_in[6], wall, bias_r, flag);
    zero_state<<<10176, 256, 0, stream>>>((float*)d_ws);

    for (int s = 0; s < 16; ++s) {
        unsigned short* hr = (s & 1) ? hp1 : hp0;
        unsigned short* hw = (s & 1) ? hp0 : hp1;
        lstm_step<<<dim3(256), 512, 0, stream>>>(d_in[0], wall, bias_r,
                                                 hr, hw, c, d_out, flag, s);
    }
}

// Round 12
// 587.259 us; speedup vs baseline: 1.4568x; 1.0088x over previous
//
#include <hip/hip_runtime.h>
#include <hip/hip_bf16.h>

// Bidirectional ConvLSTM, B=8 T=16 C=3 H=W=32 hid=64 K=7 ('SAME').
// Round 14: R13-verified kernel (592.4us) + three serial-term removals:
//   1. Single-shot exchange via 64 KB DYNAMIC LDS (attribute path proven
//      R8/R9): kg1 dumps all 16 f32x4 at once -> 5 -> 3 barriers/step.
//      R13 kernel kept verbatim as fallback if attribute refused.
//   2. hipMemsetAsync replaces zero_state kernel (R6 proved capture-safe).
//   3. s==0 epilogue skips the c read (c==0; fv*0 bit-exact).
// Everything else byte-identical to Round-13 bench (passed, 592.4us):
//   8 waves = 4 M-split x 2 K-split, 2-deep pipe, dir-in-LSB grid,
//   setprio, coalesced XB build, s==0 fast K-range, in-wave epilogue.
//
// Workspace (BYTE offsets), total 13,862,916 B:
//   hp0 : padded h ping, bf16 [dir][b][row38][col40][ic64] @ 0        (3,112,960)
//   hp1 : padded h pong                                    @ 3112960  (3,112,960)
//   c   : cell,  fp32 [dir][b][y32][x32][hid64]            @ 6225920  (4,194,304)
//   wall: bf16 [dir][ks105][oc256][k32]                    @ 10420224 (3,440,640)
//   bias: fp32 [dir][256]                                  @ 13860864 (2,048)
//   flag: int (1 = fp32 inputs)                            @ 13862912 (4)

#define HP0_B  0
#define HP1_B  3112960
#define C_B    6225920
#define WALL_B 10420224
#define BIAS_B 13860864
#define FLAG_B 13862912

using short8 = __attribute__((ext_vector_type(8))) short;
using f32x4  = __attribute__((ext_vector_type(4))) float;

__device__ __forceinline__ float sigm(float x) { return 1.0f / (1.0f + __expf(-x)); }
__device__ __forceinline__ float tanh_f(float x) {
    x = fminf(fmaxf(x, -30.0f), 30.0f);
    float e = __expf(2.0f * x);
    return (e - 1.0f) / (e + 1.0f);
}

// ---- dtype probe (verified) ---------------------------------------------
__global__ void detect_dtype(const unsigned int* __restrict__ xw, int* __restrict__ flag) {
    int lane = threadIdx.x;
    int cnt = 0;
    for (int i = 0; i < 4; ++i) {
        unsigned int w = xw[lane * 4 + i];
        unsigned int e = (w >> 7) & 0xFFu;
        cnt += (e >= 0xC0u) ? 1 : 0;
    }
#pragma unroll
    for (int off = 32; off > 0; off >>= 1) cnt += __shfl_down(cnt, off, 64);
    if (lane == 0) *flag = (cnt > 16) ? 1 : 0;
}

// ---- weights -> wall[d][ks][oc][k32] bf16 + bias ------------------------
__global__ void prep_weights(const void* __restrict__ whhf, const void* __restrict__ whhb,
                             const void* __restrict__ wihf, const void* __restrict__ wihb,
                             const void* __restrict__ bf, const void* __restrict__ bb,
                             short* __restrict__ wall, float* __restrict__ bias_r,
                             const int* __restrict__ flag) {
    int n = blockIdx.x * blockDim.x + threadIdx.x;
    const int fp32 = *flag;
    if (n < 1720320) {
        int icl = n & 31;
        int oc = (n >> 5) & 255;
        int ks = (n >> 13) % 105;
        int d = n / 860160;
        const void* hh = d ? whhb : whhf;
        const void* ih = d ? wihb : wihf;
        float v = 0.0f;
        if (ks < 98) {
            int ky = ks / 14, rr = ks % 14, kc = rr / 7, kx = rr % 7;
            int si = ((oc * 64 + kc * 32 + icl) * 7 + ky) * 7 + kx;
            v = fp32 ? ((const float*)hh)[si] : __bfloat162float(((const __hip_bfloat16*)hh)[si]);
        } else {
            int kx = ks - 98, ky = icl >> 2, ic = icl & 3;
            if (ic < 3 && ky < 7) {
                int si = ((oc * 3 + ic) * 7 + ky) * 7 + kx;
                v = fp32 ? ((const float*)ih)[si] : __bfloat162float(((const __hip_bfloat16*)ih)[si]);
            }
        }
        __hip_bfloat16 hv = __float2bfloat16(v);
        wall[n] = *(short*)&hv;
        return;
    }
    n -= 1720320;
    if (n < 512) {
        const void* src = (n >= 256) ? bb : bf;
        int j = n & 255;
        bias_r[n] = fp32 ? ((const float*)src)[j] : __bfloat162float(((const __hip_bfloat16*)src)[j]);
    }
}

// ---- MFMA step kernel (64 KB dynamic LDS, single-shot exchange) ----------
// grid 256 blocks 1D (bid: dir = bit0, b = bits1-3, ygrp = bits4-7), 512 thr
// = 8 waves (4 M-split x 2 K-split).
// LDS (65,536 B dynamic), overlaid:
//   K-loop  : h tile [8][40][72] + XB [2][40][40] = 26240 shorts (52,480 B)
//   exchange: kg=1 full partial acc, fp32 [wm4][slot16][q4][li16][4] (65,536 B)
__global__ __launch_bounds__(512, 2)
void lstm_step(const void* __restrict__ xin,
               const short* __restrict__ wall,
               const float* __restrict__ bias_r,
               const unsigned short* __restrict__ hp_r,
               unsigned short* __restrict__ hp_w,
               float* __restrict__ c,
               void* __restrict__ out,
               const int* __restrict__ flag, int s) {
    extern __shared__ short lds[];
    const int bid = blockIdx.x;
    const int dir = bid & 1;          // dir in LSB: XCD=bid%8 -> one dir per XCD
    const int b = (bid >> 1) & 7;
    const int ygrp = bid >> 4;
    const int t = dir ? (15 - s) : s;
    const int y0 = ygrp * 2;
    const int tid = threadIdx.x;
    const int wv = tid >> 6;          // 0..7
    const int kg = wv >> 2;           // K-group
    const int wm = wv & 3;            // M-split role
    const int l = tid & 63;
    const int q = l >> 4;
    const int li = l & 15;
    const int fp32 = *flag;
    const int db = dir * 8 + b;

    // stage h rows y0..y0+7 into padded LDS -- skipped at s==0 (h==0)
    if (s != 0) {
        const uint4* src = (const uint4*)(hp_r + (size_t)(db * 38 + y0) * 40 * 64);
        for (int i = tid; i < 2560; i += 512) {
            int ic8 = i & 7, col = (i >> 3) % 40, row = i / 320;
            uint4 v = src[i];
            *(uint4*)&lds[(row * 40 + col) * 72 + ic8 * 8] = v;
        }
    }
    // build XB[r][cc][k=ky*4+ic] -- cc-inner index map (coalesced, R10 win)
    for (int i = tid; i < 3200; i += 512) {
        int cc = i % 40;
        int r  = (i / 40) & 1;
        int k  = i / 80;              // 0..39
        float v = 0.0f;
        if (k < 28) {
            int ky = k >> 2, ic = k & 3;
            int yin = y0 + r + ky - 3, cin = cc - 3;
            if (ic < 3 && yin >= 0 && yin < 32 && cin >= 0 && cin < 32) {
                size_t gi = (size_t)((b * 16 + t) * 3 + ic) * 1024 + yin * 32 + cin;
                v = fp32 ? ((const float*)xin)[gi]
                         : __bfloat162float(((const __hip_bfloat16*)xin)[gi]);
            }
        }
        __hip_bfloat16 hb = __float2bfloat16(v);
        lds[23040 + (r * 40 + cc) * 40 + k] = *(short*)&hb;
    }
    __syncthreads();

    // acc init: kg=0 carries the bias, kg=1 starts at zero (partials)
    f32x4 acc[4][4];
    if (kg == 0) {
        const float* bp = bias_r + dir * 256 + wm * 16 + q * 4;
#pragma unroll
        for (int g = 0; g < 4; ++g) {
            f32x4 bv = *(const f32x4*)(bp + g * 64);
#pragma unroll
            for (int nt = 0; nt < 4; ++nt) acc[g][nt] = bv;
        }
    } else {
        f32x4 z = {0.0f, 0.0f, 0.0f, 0.0f};
#pragma unroll
        for (int g = 0; g < 4; ++g)
#pragma unroll
            for (int nt = 0; nt < 4; ++nt) acc[g][nt] = z;
    }

    // lane bases
    const short* wbase = wall + (size_t)dir * 860160 + ((wm * 16 + li) * 32 + q * 8);
    int bh[4], bx[4];
#pragma unroll
    for (int nt = 0; nt < 4; ++nt) {
        int rt = nt >> 1, ct = nt & 1;
        bh[nt] = (rt * 40 + ct * 16 + li) * 72 + q * 8;
        bx[nt] = 23040 + (rt * 40 + ct * 16 + li) * 40 + q * 8;
    }

    auto loadA = [&](short8* A, int ks) {
        const short* p = wbase + (size_t)ks * 8192;
#pragma unroll
        for (int g = 0; g < 4; ++g) A[g] = *(const short8*)(p + g * 2048);
    };
    auto loadB = [&](short8* B, int ks) {
        if (ks < 98) {
            int ky = ks / 14, rr = ks % 14;
            int uoff = ky * 2880 + (rr % 7) * 72 + (rr / 7) * 32;
#pragma unroll
            for (int nt = 0; nt < 4; ++nt) B[nt] = *(const short8*)&lds[bh[nt] + uoff];
        } else {
            int uoff = (ks - 98) * 40;
#pragma unroll
            for (int nt = 0; nt < 4; ++nt) B[nt] = *(const short8*)&lds[bx[nt] + uoff];
        }
    };
    auto mfma16 = [&](short8* A, short8* B) {
        __builtin_amdgcn_s_setprio(1);      // T5
#pragma unroll
        for (int g = 0; g < 4; ++g)
#pragma unroll
            for (int nt = 0; nt < 4; ++nt)
                acc[g][nt] = __builtin_amdgcn_mfma_f32_16x16x32_bf16(A[g], B[nt], acc[g][nt], 0, 0, 0);
        __builtin_amdgcn_s_setprio(0);
    };

    // K-loop ranges: s==0 -> h==0 exactly, only x-conv ks [98,105) needed.
    const int ks_begin = (s == 0) ? (kg ? 101 : 98) : (kg ? 52 : 0);
    const int ks_end   = (s == 0) ? (kg ? 105 : 101) : (kg ? 105 : 52);
    short8 A0[4], A1[4], B0[4], B1[4];
    loadA(A0, ks_begin); loadB(B0, ks_begin);
    int ks = ks_begin;
#pragma unroll 1
    for (; ks + 1 < ks_end; ks += 2) {
        loadA(A1, ks + 1); loadB(B1, ks + 1);
        mfma16(A0, B0);
        int kn = (ks + 2 < ks_end) ? ks + 2 : ks; // clamp (redundant reload on last iter)
        loadA(A0, kn); loadB(B0, kn);
        mfma16(A1, B1);
    }
    if (ks < ks_end) mfma16(A0, B0); // odd-count tail

    // ---- combine partials: single-shot (64 KB exchange region) -----------
    // Fully unrolled, CONSTANT acc indices only (rule #20).
    __syncthreads();           // all waves done with h-tile/XB reads
    {
        float* exch = (float*)lds;
        float* xp = exch + wm * 4096 + q * 64 + li * 4;
        if (kg == 1) {
#pragma unroll
            for (int g = 0; g < 4; ++g)
#pragma unroll
                for (int nt = 0; nt < 4; ++nt)
                    *(f32x4*)(xp + (g * 4 + nt) * 256) = acc[g][nt];
        }
        __syncthreads();
        if (kg == 0) {
#pragma unroll
            for (int g = 0; g < 4; ++g)
#pragma unroll
                for (int nt = 0; nt < 4; ++nt)
                    acc[g][nt] += *(const f32x4*)(xp + (g * 4 + nt) * 256);
        }
    }
    if (kg == 1) return;       // no barriers past this point

    // epilogue (kg=0 only; all 4 gates present in-wave)
    const int hid0 = wm * 16 + q * 4;
#pragma unroll
    for (int nt = 0; nt < 4; ++nt) {
        int y = y0 + (nt >> 1);
        int px = (nt & 1) * 16 + li;
        float* cp = c + (size_t)(db * 1024 + y * 32 + px) * 64 + hid0;
        f32x4 cold;
        if (s == 0) {          // c == 0 at s=0: skip the cold read (bit-exact)
            cold = (f32x4){0.0f, 0.0f, 0.0f, 0.0f};
        } else {
            cold = *(const f32x4*)cp;
        }
        f32x4 hv;
#pragma unroll
        for (int r = 0; r < 4; ++r) {
            float iv = sigm(acc[0][nt][r]);
            float fv = sigm(acc[1][nt][r]);
            float gv = tanh_f(acc[2][nt][r]);
            float ov = sigm(acc[3][nt][r]);
            float cn = fv * cold[r] + iv * gv;
            cold[r] = cn;
            hv[r] = ov * tanh_f(cn);
        }
        *(f32x4*)cp = cold;

        ushort4 hu;
        {
            __hip_bfloat16 t0 = __float2bfloat16(hv[0]); hu.x = *(unsigned short*)&t0;
            __hip_bfloat16 t1 = __float2bfloat16(hv[1]); hu.y = *(unsigned short*)&t1;
            __hip_bfloat16 t2 = __float2bfloat16(hv[2]); hu.z = *(unsigned short*)&t2;
            __hip_bfloat16 t3 = __float2bfloat16(hv[3]); hu.w = *(unsigned short*)&t3;
        }
        *(ushort4*)(hp_w + (size_t)((db * 38 + y + 3) * 40 + px + 3) * 64 + hid0) = hu;

        size_t ob = (size_t)((b * 16 + t) * 128 + dir * 64 + hid0) * 1024 + y * 32 + px;
        if (fp32) {
            float* op = (float*)out;
#pragma unroll
            for (int r = 0; r < 4; ++r) op[ob + (size_t)r * 1024] = hv[r];
        } else {
            __hip_bfloat16* op = (__hip_bfloat16*)out;
#pragma unroll
            for (int r = 0; r < 4; ++r) op[ob + (size_t)r * 1024] = __float2bfloat16(hv[r]);
        }
    }
}

// ---- FALLBACK: R13-verified kernel verbatim (592.4 us, passed) -----------
__global__ __launch_bounds__(512, 2)
void lstm_step_fb(const void* __restrict__ xin,
                  const short* __restrict__ wall,
                  const float* __restrict__ bias_r,
                  const unsigned short* __restrict__ hp_r,
                  unsigned short* __restrict__ hp_w,
                  float* __restrict__ c,
                  void* __restrict__ out,
                  const int* __restrict__ flag, int s) {
    const int bid = blockIdx.x;
    const int dir = bid & 1;
    const int b = (bid >> 1) & 7;
    const int ygrp = bid >> 4;
    const int t = dir ? (15 - s) : s;
    const int y0 = ygrp * 2;
    const int tid = threadIdx.x;
    const int wv = tid >> 6;
    const int kg = wv >> 2;
    const int wm = wv & 3;
    const int l = tid & 63;
    const int q = l >> 4;
    const int li = l & 15;
    const int fp32 = *flag;
    const int db = dir * 8 + b;

    __shared__ __align__(16) short lds[26240];

    if (s != 0) {
        const uint4* src = (const uint4*)(hp_r + (size_t)(db * 38 + y0) * 40 * 64);
        for (int i = tid; i < 2560; i += 512) {
            int ic8 = i & 7, col = (i >> 3) % 40, row = i / 320;
            uint4 v = src[i];
            *(uint4*)&lds[(row * 40 + col) * 72 + ic8 * 8] = v;
        }
    }
    for (int i = tid; i < 3200; i += 512) {
        int cc = i % 40;
        int r  = (i / 40) & 1;
        int k  = i / 80;
        float v = 0.0f;
        if (k < 28) {
            int ky = k >> 2, ic = k & 3;
            int yin = y0 + r + ky - 3, cin = cc - 3;
            if (ic < 3 && yin >= 0 && yin < 32 && cin >= 0 && cin < 32) {
                size_t gi = (size_t)((b * 16 + t) * 3 + ic) * 1024 + yin * 32 + cin;
                v = fp32 ? ((const float*)xin)[gi]
                         : __bfloat162float(((const __hip_bfloat16*)xin)[gi]);
            }
        }
        __hip_bfloat16 hb = __float2bfloat16(v);
        lds[23040 + (r * 40 + cc) * 40 + k] = *(short*)&hb;
    }
    __syncthreads();

    f32x4 acc[4][4];
    if (kg == 0) {
        const float* bp = bias_r + dir * 256 + wm * 16 + q * 4;
#pragma unroll
        for (int g = 0; g < 4; ++g) {
            f32x4 bv = *(const f32x4*)(bp + g * 64);
#pragma unroll
            for (int nt = 0; nt < 4; ++nt) acc[g][nt] = bv;
        }
    } else {
        f32x4 z = {0.0f, 0.0f, 0.0f, 0.0f};
#pragma unroll
        for (int g = 0; g < 4; ++g)
#pragma unroll
            for (int nt = 0; nt < 4; ++nt) acc[g][nt] = z;
    }

    const short* wbase = wall + (size_t)dir * 860160 + ((wm * 16 + li) * 32 + q * 8);
    int bh[4], bx[4];
#pragma unroll
    for (int nt = 0; nt < 4; ++nt) {
        int rt = nt >> 1, ct = nt & 1;
        bh[nt] = (rt * 40 + ct * 16 + li) * 72 + q * 8;
        bx[nt] = 23040 + (rt * 40 + ct * 16 + li) * 40 + q * 8;
    }

    auto loadA = [&](short8* A, int ks) {
        const short* p = wbase + (size_t)ks * 8192;
#pragma unroll
        for (int g = 0; g < 4; ++g) A[g] = *(const short8*)(p + g * 2048);
    };
    auto loadB = [&](short8* B, int ks) {
        if (ks < 98) {
            int ky = ks / 14, rr = ks % 14;
            int uoff = ky * 2880 + (rr % 7) * 72 + (rr / 7) * 32;
#pragma unroll
            for (int nt = 0; nt < 4; ++nt) B[nt] = *(const short8*)&lds[bh[nt] + uoff];
        } else {
            int uoff = (ks - 98) * 40;
#pragma unroll
            for (int nt = 0; nt < 4; ++nt) B[nt] = *(const short8*)&lds[bx[nt] + uoff];
        }
    };
    auto mfma16 = [&](short8* A, short8* B) {
        __builtin_amdgcn_s_setprio(1);
#pragma unroll
        for (int g = 0; g < 4; ++g)
#pragma unroll
            for (int nt = 0; nt < 4; ++nt)
                acc[g][nt] = __builtin_amdgcn_mfma_f32_16x16x32_bf16(A[g], B[nt], acc[g][nt], 0, 0, 0);
        __builtin_amdgcn_s_setprio(0);
    };

    const int ks_begin = (s == 0) ? (kg ? 101 : 98) : (kg ? 52 : 0);
    const int ks_end   = (s == 0) ? (kg ? 105 : 101) : (kg ? 105 : 52);
    short8 A0[4], A1[4], B0[4], B1[4];
    loadA(A0, ks_begin); loadB(B0, ks_begin);
    int ks = ks_begin;
#pragma unroll 1
    for (; ks + 1 < ks_end; ks += 2) {
        loadA(A1, ks + 1); loadB(B1, ks + 1);
        mfma16(A0, B0);
        int kn = (ks + 2 < ks_end) ? ks + 2 : ks;
        loadA(A0, kn); loadB(B0, kn);
        mfma16(A1, B1);
    }
    if (ks < ks_end) mfma16(A0, B0);

    __syncthreads();
    {
        float* exch = (float*)lds;
        float* xp = exch + wm * 2048 + q * 64 + li * 4;
        if (kg == 1) {
#pragma unroll
            for (int g = 0; g < 2; ++g)
#pragma unroll
                for (int nt = 0; nt < 4; ++nt)
                    *(f32x4*)(xp + (g * 4 + nt) * 256) = acc[g][nt];
        }
        __syncthreads();
        if (kg == 0) {
#pragma unroll
            for (int g = 0; g < 2; ++g)
#pragma unroll
                for (int nt = 0; nt < 4; ++nt)
                    acc[g][nt] += *(const f32x4*)(xp + (g * 4 + nt) * 256);
        }
        __syncthreads();
        if (kg == 1) {
#pragma unroll
            for (int g = 0; g < 2; ++g)
#pragma unroll
                for (int nt = 0; nt < 4; ++nt)
                    *(f32x4*)(xp + (g * 4 + nt) * 256) = acc[2 + g][nt];
        }
        __syncthreads();
        if (kg == 0) {
#pragma unroll
            for (int g = 0; g < 2; ++g)
#pragma unroll
                for (int nt = 0; nt < 4; ++nt)
                    acc[2 + g][nt] += *(const f32x4*)(xp + (g * 4 + nt) * 256);
        }
    }
    if (kg == 1) return;

    const int hid0 = wm * 16 + q * 4;
#pragma unroll
    for (int nt = 0; nt < 4; ++nt) {
        int y = y0 + (nt >> 1);
        int px = (nt & 1) * 16 + li;
        float* cp = c + (size_t)(db * 1024 + y * 32 + px) * 64 + hid0;
        f32x4 cold = *(const f32x4*)cp;
        f32x4 hv;
#pragma unroll
        for (int r = 0; r < 4; ++r) {
            float iv = sigm(acc[0][nt][r]);
            float fv = sigm(acc[1][nt][r]);
            float gv = tanh_f(acc[2][nt][r]);
            float ov = sigm(acc[3][nt][r]);
            float cn = fv * cold[r] + iv * gv;
            cold[r] = cn;
            hv[r] = ov * tanh_f(cn);
        }
        *(f32x4*)cp = cold;

        ushort4 hu;
        {
            __hip_bfloat16 t0 = __float2bfloat16(hv[0]); hu.x = *(unsigned short*)&t0;
            __hip_bfloat16 t1 = __float2bfloat16(hv[1]); hu.y = *(unsigned short*)&t1;
            __hip_bfloat16 t2 = __float2bfloat16(hv[2]); hu.z = *(unsigned short*)&t2;
            __hip_bfloat16 t3 = __float2bfloat16(hv[3]); hu.w = *(unsigned short*)&t3;
        }
        *(ushort4*)(hp_w + (size_t)((db * 38 + y + 3) * 40 + px + 3) * 64 + hid0) = hu;

        size_t ob = (size_t)((b * 16 + t) * 128 + dir * 64 + hid0) * 1024 + y * 32 + px;
        if (fp32) {
            float* op = (float*)out;
#pragma unroll
            for (int r = 0; r < 4; ++r) op[ob + (size_t)r * 1024] = hv[r];
        } else {
            __hip_bfloat16* op = (__hip_bfloat16*)out;
#pragma unroll
            for (int r = 0; r < 4; ++r) op[ob + (size_t)r * 1024] = __float2bfloat16(hv[r]);
        }
    }
}

extern "C" void kernel_launch(void* const* d_in, const int* in_sizes, int n_in,
                              void* d_out, int out_size, void* d_ws, size_t ws_size,
                              hipStream_t stream) {
    char* wsb = (char*)d_ws;
    unsigned short* hp0 = (unsigned short*)(wsb + HP0_B);
    unsigned short* hp1 = (unsigned short*)(wsb + HP1_B);
    float* c = (float*)(wsb + C_B);
    short* wall = (short*)(wsb + WALL_B);
    float* bias_r = (float*)(wsb + BIAS_B);
    int* flag = (int*)(wsb + FLAG_B);

    static int big_lds_ok = -1;
    if (big_lds_ok < 0) {
        hipError_t e = hipFuncSetAttribute((const void*)lstm_step,
                                           hipFuncAttributeMaxDynamicSharedMemorySize,
                                           65536);
        big_lds_ok = (e == hipSuccess) ? 1 : 0;
    }

    // inputs: 0=x 1=w_ih_f 2=w_hh_f 3=b_f 4=w_ih_b 5=w_hh_b 6=b_b
    hipMemsetAsync(d_ws, 0, 10420224, stream);   // hp0+hp1+c (capture-safe, R6)
    detect_dtype<<<1, 64, 0, stream>>>((const unsigned int*)d_in[0], flag);
    prep_weights<<<6722, 256, 0, stream>>>(d_in[2], d_in[5], d_in[1], d_in[4],
                                           d_in[3], d_in[6], wall, bias_r, flag);

    if (big_lds_ok) {
        for (int s = 0; s < 16; ++s) {
            unsigned short* hr = (s & 1) ? hp1 : hp0;
            unsigned short* hw = (s & 1) ? hp0 : hp1;
            lstm_step<<<dim3(256), 512, 65536, stream>>>(d_in[0], wall, bias_r,
                                                         hr, hw, c, d_out, flag, s);
        }
    } else {
        for (int s = 0; s < 16; ++s) {
            unsigned short* hr = (s & 1) ? hp1 : hp0;
            unsigned short* hw = (s & 1) ? hp0 : hp1;
            lstm_step_fb<<<dim3(256), 512, 0, stream>>>(d_in[0], wall, bias_r,
                                                        hr, hw, c, d_out, flag, s);
        }
    }
}